// Round 11
// baseline (675.358 us; speedup 1.0000x reference)
//
#include <hip/hip_runtime.h>
#include <stdint.h>

#define D 256
#define RREL 16
#define BB 8
#define K9 2304          // (BB+1)*D
#define LN_EPS 1e-5f
#define NT (K9 / 64)     // 36 K-steps
#define BUFB 49152       // bytes per LDS buffer: A 16384 + B 32768

typedef __attribute__((ext_vector_type(8))) short frag8;
typedef __attribute__((ext_vector_type(4))) float floatx4;
typedef __attribute__((ext_vector_type(2))) float float2v;
typedef __attribute__((ext_vector_type(2))) unsigned int uint2v;   // clang vec, NT-store legal

__device__ __forceinline__ unsigned short f2bf(float f) {
    union { float f; uint32_t u; } v; v.f = f;
    uint32_t r = (v.u + 0x7FFFu + ((v.u >> 16) & 1u)) >> 16;
    return (unsigned short)r;
}
__device__ __forceinline__ float bf2f(unsigned short u) {
    union { uint32_t u; float f; } v; v.u = (uint32_t)u << 16;
    return v.f;
}
// decode a dword holding 2 bf16 -> {lo, hi} floats (2 VALU ops, exact)
__device__ __forceinline__ float2v bfpair(uint32_t d) {
    union { uint32_t u; float f; } lo, hi;
    lo.u = d << 16; hi.u = d & 0xFFFF0000u;
    return (float2v){lo.f, hi.f};
}

// packed fp32 math (full-rate, 2 FLOP-lanes per issue slot)
__device__ __forceinline__ float2v pk_mul(float2v a, float2v b) {
    float2v d;
    asm("v_pk_mul_f32 %0, %1, %2" : "=v"(d) : "v"(a), "v"(b));
    return d;
}
// acc += c * broadcast(x.lo)
__device__ __forceinline__ void pk_fma_lo(float2v& acc, float2v c, float2v x) {
    asm("v_pk_fma_f32 %0, %1, %2, %0 op_sel:[0,0,0] op_sel_hi:[1,0,1]"
        : "+v"(acc) : "v"(c), "v"(x));
}
// acc += c * broadcast(x.hi)
__device__ __forceinline__ void pk_fma_hi(float2v& acc, float2v c, float2v x) {
    asm("v_pk_fma_f32 %0, %1, %2, %0 op_sel:[0,1,0] op_sel_hi:[1,1,1]"
        : "+v"(acc) : "v"(c), "v"(x));
}

__device__ __forceinline__ void gl2lds16(const unsigned short* g, char* l) {
    __builtin_amdgcn_global_load_lds((const __attribute__((address_space(1))) void*)g,
                                     (__attribute__((address_space(3))) void*)l, 16, 0, 0);
}

// non-temporal 8B store of 4 bf16: G is write-once, read-once-later (and
// gemm's FETCH proves the read misses L3 anyway) -- keep it from evicting xb.
// Payload reinterpreted as a clang ext-vector (builtin rejects HIP_vector_type).
__device__ __forceinline__ void nt_store4(unsigned short* p, ushort4 v) {
    uint2v u;
    u.x = (uint32_t)v.x | ((uint32_t)v.y << 16);
    u.y = (uint32_t)v.z | ((uint32_t)v.w << 16);
    __builtin_nontemporal_store(u, (uint2v*)p);
}

// ---------- fp32 -> bf16 bulk convert ----------
__global__ __launch_bounds__(256) void k_cvt(const float* __restrict__ src,
                                             unsigned short* __restrict__ dst, int n4) {
    int i = blockIdx.x * 256 + threadIdx.x;
    if (i >= n4) return;
    float4 v = ((const float4*)src)[i];
    ushort4 o = make_ushort4(f2bf(v.x), f2bf(v.y), f2bf(v.z), f2bf(v.w));
    ((ushort4*)dst)[i] = o;
}

// ---------- CSR-by-destination ----------
// 8 edges/thread (grid-strided, coalesced): 8 independent atomic chains.
__global__ __launch_bounds__(256) void k_deg(const int* __restrict__ ei,
                                             int* __restrict__ deg, int E) {
    int t = blockIdx.x * 256 + threadIdx.x;
    int stride = gridDim.x * 256;
    int d[8];
#pragma unroll
    for (int j = 0; j < 8; ++j) {
        int e = t + j * stride;
        d[j] = (e < E) ? ei[E + e] : -1;
    }
#pragma unroll
    for (int j = 0; j < 8; ++j)
        if (d[j] >= 0) atomicAdd(&deg[d[j]], 1);
}

__global__ __launch_bounds__(256) void k_scan1(const int* __restrict__ deg,
                                               int* __restrict__ csum, int N) {
    __shared__ int sh[256];
    int n = blockIdx.x * 256 + threadIdx.x;
    sh[threadIdx.x] = (n < N) ? deg[n] : 0;
    __syncthreads();
    for (int off = 128; off > 0; off >>= 1) {
        if (threadIdx.x < off) sh[threadIdx.x] += sh[threadIdx.x + off];
        __syncthreads();
    }
    if (threadIdx.x == 0) csum[blockIdx.x] = sh[0];
}

// scan3 with the chunk-prefix scan folded in (scan2 kernel deleted):
// each block redundantly scans the <=256-entry csum array to get its own
// chunk base, then does the per-node scan. csum is read-only here.
__global__ __launch_bounds__(256) void k_scan3(const int* __restrict__ deg,
                                               const int* __restrict__ csum, int nch,
                                               int* __restrict__ rowptr,
                                               int* __restrict__ cursor,
                                               float* __restrict__ cnt, int N) {
    __shared__ int sh[256];
    int tid = threadIdx.x;
    int bid = blockIdx.x;
    int base;
    if (nch <= 256) {
        int c = (tid < nch) ? csum[tid] : 0;
        sh[tid] = c;
        __syncthreads();
        for (int off = 1; off < 256; off <<= 1) {
            int t = (tid >= off) ? sh[tid - off] : 0;
            __syncthreads();
            sh[tid] += t;
            __syncthreads();
        }
        base = sh[bid] - csum[bid];                 // exclusive prefix for this chunk
        if (bid == 0 && tid == 255) rowptr[N] = sh[255];   // grand total
        __syncthreads();                            // sh[] reused below
    } else {                                        // robustness fallback (unused at N=50000)
        int s = 0;
        for (int i = 0; i < bid; ++i) s += csum[i];
        base = s;
        if (bid == 0 && tid == 0) {
            int tot = 0;
            for (int i = 0; i < nch; ++i) tot += csum[i];
            rowptr[N] = tot;
        }
    }
    int n = bid * 256 + tid;
    int v = (n < N) ? deg[n] : 0;
    sh[tid] = v;
    __syncthreads();
    for (int off = 1; off < 256; off <<= 1) {
        int t = (tid >= off) ? sh[tid - off] : 0;
        __syncthreads();
        sh[tid] += t;
        __syncthreads();
    }
    int excl = sh[tid] - v + base;
    if (n < N) {
        rowptr[n] = excl;
        cursor[n] = excl;
        cnt[n] = (float)(v + 1);
    }
}

__global__ __launch_bounds__(256) void k_scatter(const int* __restrict__ ei,
                                                 const int* __restrict__ et,
                                                 const float* __restrict__ ea,
                                                 int* __restrict__ cursor,
                                                 int2* __restrict__ ep, int E) {
    int t = blockIdx.x * 256 + threadIdx.x;
    int stride = gridDim.x * 256;
    int src[8], dst[8], typ[8]; float w[8]; bool v[8];
#pragma unroll
    for (int j = 0; j < 8; ++j) {
        int e = t + j * stride;
        v[j] = (e < E);
        if (v[j]) { src[j] = ei[e]; dst[j] = ei[E + e]; typ[j] = et[e]; w[j] = ea[e]; }
    }
    int p[8];
#pragma unroll
    for (int j = 0; j < 8; ++j)
        if (v[j]) p[j] = atomicAdd(&cursor[dst[j]], 1);
#pragma unroll
    for (int j = 0; j < 8; ++j)
        if (v[j]) ep[p[j]] = make_int2(src[j] | (typ[j] << 24), __float_as_int(w[j]));
}

// ---------- weight prep: Wt[o][k] bf16, k = b*256+i (b=8 -> root) ----------
__global__ __launch_bounds__(256) void k_prep_w(const float* __restrict__ basis,
                                                const float* __restrict__ root,
                                                unsigned short* __restrict__ Wt) {
    __shared__ float tile[64][65];
    int k0 = blockIdx.x * 64, o0 = blockIdx.y * 64;
    const float* src = (k0 < BB * D) ? (basis + (size_t)k0 * D)
                                     : (root + (size_t)(k0 - BB * D) * D);
    int tid = threadIdx.x;
#pragma unroll
    for (int t = 0; t < 16; ++t) {
        int idx = t * 256 + tid;
        int kk = idx >> 6, oo = idx & 63;
        tile[kk][oo] = src[(size_t)kk * D + o0 + oo];
    }
    __syncthreads();
#pragma unroll
    for (int t = 0; t < 16; ++t) {
        int idx = t * 256 + tid;
        int oo = idx >> 6, kk = idx & 63;
        Wt[(size_t)(o0 + oo) * K9 + k0 + kk] = f2bf(tile[kk][oo]);
    }
}

// ---------- gather: one wave per node (one-shot dispatch; persistent form
// regressed in R9: static group assignment lost the HW scheduler's dynamic
// load balancing over skewed edge counts) ----------
__device__ __forceinline__ void edge_fma(float2v g2[4][4], float2v c0, float2v c1,
                                         float2v c2, float2v c3,
                                         float2v x0, float2v x1) {
    pk_fma_lo(g2[0][0], c0, x0); pk_fma_lo(g2[1][0], c1, x0);
    pk_fma_lo(g2[2][0], c2, x0); pk_fma_lo(g2[3][0], c3, x0);
    pk_fma_hi(g2[0][1], c0, x0); pk_fma_hi(g2[1][1], c1, x0);
    pk_fma_hi(g2[2][1], c2, x0); pk_fma_hi(g2[3][1], c3, x0);
    pk_fma_lo(g2[0][2], c0, x1); pk_fma_lo(g2[1][2], c1, x1);
    pk_fma_lo(g2[2][2], c2, x1); pk_fma_lo(g2[3][2], c3, x1);
    pk_fma_hi(g2[0][3], c0, x1); pk_fma_hi(g2[1][3], c1, x1);
    pk_fma_hi(g2[3][3], c3, x1); pk_fma_hi(g2[2][3], c2, x1);
}

__device__ __forceinline__ void do_edge(float2v g2[4][4], const float* att_s,
                                        int2 pe, uint2 ud) {
    int r = (unsigned)pe.x >> 24;
    const float4* Ar = (const float4*)&att_s[r * BB];
    float4 a0 = Ar[0], a1 = Ar[1];
    float we = __int_as_float(pe.y);
    float2v w2 = {we, we};
    float2v c0 = pk_mul(w2, (float2v){a0.x, a0.y});
    float2v c1 = pk_mul(w2, (float2v){a0.z, a0.w});
    float2v c2 = pk_mul(w2, (float2v){a1.x, a1.y});
    float2v c3 = pk_mul(w2, (float2v){a1.z, a1.w});
    float2v x0 = bfpair(ud.x), x1 = bfpair(ud.y);
    edge_fma(g2, c0, c1, c2, c3, x0, x1);
}

__global__ __launch_bounds__(256) void k_gather(
    const unsigned short* __restrict__ xb, const float* __restrict__ att,
    const int* __restrict__ rowptr, const int2* __restrict__ ep,
    const float* __restrict__ cnt, unsigned short* __restrict__ G,
    int n0, int rows, int N) {
    __shared__ __align__(32) float att_s[RREL * BB];
    int tid = threadIdx.x;
    if (tid < RREL * BB) att_s[tid] = att[tid];
    __syncthreads();
    int wv = tid >> 6, lane = tid & 63;
    int rloc = blockIdx.x * 4 + wv;
    if (rloc >= rows) return;
    int n = n0 + rloc;
    unsigned short* gout = G + (size_t)rloc * K9 + lane * 4;
    if (n >= N) {
        ushort4 z = make_ushort4(0, 0, 0, 0);
#pragma unroll
        for (int b = 0; b <= BB; ++b) nt_store4(gout + b * D, z);
        return;
    }
    uint2 xu = *(const uint2*)&xb[(size_t)n * D + lane * 4];
    float2v xs0 = bfpair(xu.x), xs1 = bfpair(xu.y);
    float xv[4] = {xs0.x, xs0.y, xs1.x, xs1.y};

    float2v g2[4][4];
#pragma unroll
    for (int bp = 0; bp < 4; ++bp) {
        float2v ap = {att_s[(RREL - 1) * BB + 2 * bp],
                      att_s[(RREL - 1) * BB + 2 * bp + 1]};
#pragma unroll
        for (int j = 0; j < 4; ++j) {
            float2v xs = {xv[j], xv[j]};
            g2[bp][j] = ap * xs;
        }
    }

    int e0 = rowptr[n], e1 = rowptr[n + 1];
    int e = e0;
    for (; e + 4 <= e1; e += 4) {
        int2 pa = ep[e], pb = ep[e + 1], pc = ep[e + 2], pd = ep[e + 3];
        uint2 uA = *(const uint2*)&xb[(size_t)(pa.x & 0xFFFFFF) * D + lane * 4];
        uint2 uB = *(const uint2*)&xb[(size_t)(pb.x & 0xFFFFFF) * D + lane * 4];
        uint2 uC = *(const uint2*)&xb[(size_t)(pc.x & 0xFFFFFF) * D + lane * 4];
        uint2 uD = *(const uint2*)&xb[(size_t)(pd.x & 0xFFFFFF) * D + lane * 4];
        __builtin_amdgcn_sched_barrier(0);   // loads above, FMAs below
        do_edge(g2, att_s, pa, uA);
        do_edge(g2, att_s, pb, uB);
        do_edge(g2, att_s, pc, uC);
        do_edge(g2, att_s, pd, uD);
    }
    if (e + 2 <= e1) {
        int2 pa = ep[e], pb = ep[e + 1];
        uint2 uA = *(const uint2*)&xb[(size_t)(pa.x & 0xFFFFFF) * D + lane * 4];
        uint2 uB = *(const uint2*)&xb[(size_t)(pb.x & 0xFFFFFF) * D + lane * 4];
        __builtin_amdgcn_sched_barrier(0);
        do_edge(g2, att_s, pa, uA);
        do_edge(g2, att_s, pb, uB);
        e += 2;
    }
    if (e < e1) {
        int2 pa = ep[e];
        uint2 uA = *(const uint2*)&xb[(size_t)(pa.x & 0xFFFFFF) * D + lane * 4];
        do_edge(g2, att_s, pa, uA);
    }
#pragma unroll
    for (int bp = 0; bp < 4; ++bp) {
        ushort4 o0 = make_ushort4(f2bf(g2[bp][0].x), f2bf(g2[bp][1].x),
                                  f2bf(g2[bp][2].x), f2bf(g2[bp][3].x));
        nt_store4(gout + (2 * bp) * D, o0);
        ushort4 o1 = make_ushort4(f2bf(g2[bp][0].y), f2bf(g2[bp][1].y),
                                  f2bf(g2[bp][2].y), f2bf(g2[bp][3].y));
        nt_store4(gout + (2 * bp + 1) * D, o1);
    }
    float cn = cnt[n];
    ushort4 o = make_ushort4(f2bf(cn * xv[0]), f2bf(cn * xv[1]),
                             f2bf(cn * xv[2]), f2bf(cn * xv[3]));
    nt_store4(gout + BB * D, o);
}

// ---------- fused GEMM (128x256, K=2304, bf16 MFMA) + mean + residual + LN + ReLU ----------
// R5-proven structure (measured 54-56 us): 1024 thr / 16 waves / acc[2][4],
// 2-buffer prefetch + __syncthreads. Structural departures both regressed:
// R6 fat-waves (62 us), R7 counted-vmcnt 3-buf (67 us). FROZEN.
__global__ __launch_bounds__(1024, 4) void k_gemm(
    const unsigned short* __restrict__ G, const unsigned short* __restrict__ Wt,
    const float* __restrict__ hin, const float* __restrict__ cnt,
    const float* __restrict__ bias, const float* __restrict__ gln,
    const float* __restrict__ bln, float* __restrict__ hout,
    unsigned short* __restrict__ houtb, int n0, int N) {
    __shared__ __align__(16) char smem[2 * BUFB];
    // post-loop aliases (staging region idle during the epilogue)
    float* ps   = (float*)smem;          // [128][4] row-sum partials per col-wave
    float* pq   = ps + 512;              // [128][4]
    float* mu_s = ps + 1024;             // [128]
    float* rs_s = ps + 1152;             // [128]

    int tid = threadIdx.x;
    int wv = tid >> 6, lane = tid & 63;
    int quad = lane >> 4, l16 = lane & 15;
    int wm = wv >> 2, wn = wv & 3;       // wave -> 32x64 sub-tile of 128x256
    int grow = blockIdx.x * 128;         // chunk-local row base
    int nb = n0 + grow;                  // global node base

    // staging addresses (XOR-swizzled 16B granules: slot = g ^ (row&7))
    int arow_s = tid >> 3, aslot_s = tid & 7;     // A: 128 rows x 8 granules
    const unsigned short* gA =
        G + (size_t)(grow + arow_s) * K9 + ((aslot_s ^ (arow_s & 7)) << 3);
    char* lA = smem + (tid << 4);
    const unsigned short* gB[2]; char* lB[2];
#pragma unroll
    for (int t = 0; t < 2; ++t) {                  // B: 256 rows x 8 granules
        int c = t * 1024 + tid;
        int brow = c >> 3, bslot = c & 7;
        gB[t] = Wt + (size_t)brow * K9 + ((bslot ^ (brow & 7)) << 3);
        lB[t] = smem + 16384 + (c << 4);
    }

    floatx4 acc[2][4];
#pragma unroll
    for (int mf = 0; mf < 2; ++mf)
#pragma unroll
        for (int nf = 0; nf < 4; ++nf) acc[mf][nf] = (floatx4){0.f, 0.f, 0.f, 0.f};

    auto STAGE = [&](int it, int soff) {
        int koff = it * 64;
        gl2lds16(gA + koff, lA + soff);
        gl2lds16(gB[0] + koff, lB[0] + soff);
        gl2lds16(gB[1] + koff, lB[1] + soff);
    };
    auto COMPUTE = [&](int soff) {
        const char* Ab = smem + soff;
        const char* Bb = Ab + 16384;
#pragma unroll
        for (int kc = 0; kc < 2; ++kc) {
            int g = kc * 4 + quad;
            frag8 a[2], b[4];
#pragma unroll
            for (int mf = 0; mf < 2; ++mf) {
                int arow = wm * 32 + mf * 16 + l16;
                a[mf] = *(const frag8*)(Ab + arow * 128 + ((g ^ (arow & 7)) << 4));
            }
#pragma unroll
            for (int nf = 0; nf < 4; ++nf) {
                int brow = wn * 64 + nf * 16 + l16;
                b[nf] = *(const frag8*)(Bb + brow * 128 + ((g ^ (brow & 7)) << 4));
            }
#pragma unroll
            for (int mf = 0; mf < 2; ++mf)
#pragma unroll
                for (int nf = 0; nf < 4; ++nf)
                    acc[mf][nf] = __builtin_amdgcn_mfma_f32_16x16x32_bf16(
                        a[mf], b[nf], acc[mf][nf], 0, 0, 0);
        }
    };

    STAGE(0, 0);
    __syncthreads();
    for (int it = 0; it < NT; it += 2) {            // NT = 36 (even)
        STAGE(it + 1, BUFB);                        // prefetch buf1; lands during compute
        COMPUTE(0);
        __syncthreads();
        if (it + 2 < NT) STAGE(it + 2, 0);
        COMPUTE(BUFB);
        __syncthreads();
    }

    // ---- pass 1: val = acc/cnt + residual + bias; wave-local LN partials ----
    int col[4]; float bic[4];
#pragma unroll
    for (int nf = 0; nf < 4; ++nf) {
        col[nf] = wn * 64 + nf * 16 + l16;
        bic[nf] = bias[col[nf]];
    }
#pragma unroll
    for (int mf = 0; mf < 2; ++mf) {
#pragma unroll
        for (int r = 0; r < 4; ++r) {
            int row = wm * 32 + mf * 16 + quad * 4 + r;
            int n = nb + row;
            float s = 0.f, sq = 0.f;
            if (n < N) {
                float inv = 1.0f / cnt[n];
                const float* hp = hin + (size_t)n * D;
#pragma unroll
                for (int nf = 0; nf < 4; ++nf) {
                    float v = acc[mf][nf][r] * inv + hp[col[nf]] + bic[nf];
                    acc[mf][nf][r] = v;
                    s += v; sq += v * v;
                }
            }
            s += __shfl_xor(s, 1); sq += __shfl_xor(sq, 1);
            s += __shfl_xor(s, 2); sq += __shfl_xor(sq, 2);
            s += __shfl_xor(s, 4); sq += __shfl_xor(sq, 4);
            s += __shfl_xor(s, 8); sq += __shfl_xor(sq, 8);
            if (l16 == 0) {
                ps[row * 4 + wn] = s;
                pq[row * 4 + wn] = sq;
            }
        }
    }
    __syncthreads();
    if (tid < 128) {
        float s  = ps[tid * 4] + ps[tid * 4 + 1] + ps[tid * 4 + 2] + ps[tid * 4 + 3];
        float sq = pq[tid * 4] + pq[tid * 4 + 1] + pq[tid * 4 + 2] + pq[tid * 4 + 3];
        float mu = s * (1.f / D);
        mu_s[tid] = mu;
        rs_s[tid] = rsqrtf(sq * (1.f / D) - mu * mu + LN_EPS);
    }
    __syncthreads();

    // ---- pass 2: normalize + ReLU + store (fp32, optional bf16 copy) ----
    float gc[4], bc[4];
#pragma unroll
    for (int nf = 0; nf < 4; ++nf) {
        gc[nf] = gln[col[nf]];
        bc[nf] = bln[col[nf]];
    }
#pragma unroll
    for (int mf = 0; mf < 2; ++mf) {
#pragma unroll
        for (int r = 0; r < 4; ++r) {
            int row = wm * 32 + mf * 16 + quad * 4 + r;
            int n = nb + row;
            if (n >= N) continue;
            float mu = mu_s[row], rs = rs_s[row];
            float* op = hout + (size_t)n * D;
#pragma unroll
            for (int nf = 0; nf < 4; ++nf) {
                float o = fmaxf((acc[mf][nf][r] - mu) * rs * gc[nf] + bc[nf], 0.f);
                op[col[nf]] = o;
                if (houtb) houtb[(size_t)n * D + col[nf]] = f2bf(o);
            }
        }
    }
}

extern "C" void kernel_launch(void* const* d_in, const int* in_sizes, int n_in,
                              void* d_out, int out_size, void* d_ws, size_t ws_size,
                              hipStream_t stream) {
    const float* x      = (const float*)d_in[0];
    const int*   ei     = (const int*)d_in[1];
    const int*   et     = (const int*)d_in[2];
    const float* ea     = (const float*)d_in[3];
    const float* basis1 = (const float*)d_in[4];
    const float* att1   = (const float*)d_in[5];
    const float* root1  = (const float*)d_in[6];
    const float* bias1  = (const float*)d_in[7];
    const float* g1     = (const float*)d_in[8];
    const float* b1     = (const float*)d_in[9];
    const float* basis2 = (const float*)d_in[10];
    const float* att2   = (const float*)d_in[11];
    const float* root2  = (const float*)d_in[12];
    const float* bias2  = (const float*)d_in[13];
    const float* g2     = (const float*)d_in[14];
    const float* b2     = (const float*)d_in[15];
    float* out = (float*)d_out;

    int N = in_sizes[0] / D;
    int E = in_sizes[2];
    int nch = (N + 255) / 256;
    int Mp = ((N + 63) / 64) * 64;
    int T = Mp / 64;
    int Tpad = (T + 1) & ~1;             // even # of 64-row tiles (gather zero-fills pads)

    char* p = (char*)d_ws;
    size_t used = 0;
    auto alloc = [&](size_t bytes) {
        char* q = p;
        size_t a = (bytes + 255) & ~(size_t)255;
        p += a; used += a;
        return q;
    };
    float*          h1     = (float*)alloc((size_t)N * D * 4);
    unsigned short* xb     = (unsigned short*)alloc((size_t)N * D * 2);
    unsigned short* h1b    = (unsigned short*)alloc((size_t)N * D * 2);
    unsigned short* Wt     = (unsigned short*)alloc((size_t)K9 * D * 2);
    int*            deg    = (int*)alloc((size_t)N * 4);
    int*            rowptr = (int*)alloc((size_t)(N + 1) * 4);
    int*            cursor = (int*)alloc((size_t)N * 4);
    float*          cnt    = (float*)alloc((size_t)N * 4);
    int2*           ep     = (int2*)alloc((size_t)E * 8);
    int*            csum   = (int*)alloc((size_t)nch * 4);
    size_t remain = (ws_size > used + 256) ? (ws_size - used - 256) : 0;
    size_t tile_bytes = (size_t)64 * K9 * 2;
    int ct_max = (int)(remain / tile_bytes);
    if (ct_max < 2) ct_max = 2;
    if (ct_max > Tpad) ct_max = Tpad;
    unsigned short* G = (unsigned short*)alloc((size_t)ct_max * tile_bytes);

    // balanced, even chunk size (in 64-row tiles) -> each gemm grid <= ~256
    // blocks of 128 rows, one round per chunk, rows % 128 == 0 per chunk.
    int nch2 = (Tpad + ct_max - 1) / ct_max;
    int ct = (Tpad + nch2 - 1) / nch2;
    ct = (ct + 1) & ~1;
    if (ct > ct_max) ct = ct_max & ~1;
    if (ct < 2) ct = 2;

    hipMemsetAsync(deg, 0, (size_t)N * 4, stream);
    int gE8 = (E + 2047) / 2048;         // 8 edges/thread
    k_deg<<<gE8, 256, 0, stream>>>(ei, deg, E);
    k_scan1<<<nch, 256, 0, stream>>>(deg, csum, N);
    k_scan3<<<nch, 256, 0, stream>>>(deg, csum, nch, rowptr, cursor, cnt, N);
    k_scatter<<<gE8, 256, 0, stream>>>(ei, et, ea, cursor, ep, E);
    k_cvt<<<(N * D / 4 + 255) / 256, 256, 0, stream>>>(x, xb, N * D / 4);

    const float* bas[2]  = {basis1, basis2};
    const float* attp[2] = {att1, att2};
    const float* rt[2]   = {root1, root2};
    const float* bi[2]   = {bias1, bias2};
    const float* lg[2]   = {g1, g2};
    const float* lb[2]   = {b1, b2};
    const unsigned short* gin[2] = {xb, h1b};
    const float* hres[2] = {x, h1};
    float*          hof[2] = {h1, out};
    unsigned short* hob[2] = {h1b, nullptr};

    for (int L = 0; L < 2; ++L) {
        k_prep_w<<<dim3(K9 / 64, D / 64), 256, 0, stream>>>(bas[L], rt[L], Wt);
        for (int c0 = 0; c0 < Tpad; c0 += ct) {
            int tiles = (Tpad - c0 < ct) ? (Tpad - c0) : ct;
            int rows = tiles * 64;       // multiple of 128 by construction
            int n0 = c0 * 64;
            k_gather<<<rows / 4, 256, 0, stream>>>(gin[L], attp[L], rowptr, ep,
                                                   cnt, G, n0, rows, N);
            k_gemm<<<rows / 128, 1024, 0, stream>>>(G, Wt, hres[L], cnt, bi[L],
                                                    lg[L], lb[L], hof[L], hob[L],
                                                    n0, N);
        }
    }
}

// Round 12
// 618.040 us; speedup vs baseline: 1.0927x; 1.0927x over previous
//
#include <hip/hip_runtime.h>
#include <stdint.h>

#define D 256
#define RREL 16
#define BB 8
#define K9 2304          // B (Wt) K-extent: (BB+1)*D
#define KG 2048          // G row width: BB*D (9th block eliminated, staged from xb)
#define LN_EPS 1e-5f
#define NT (K9 / 64)     // 36 K-steps total (32 from G, 4 from xb)
#define BUFB 49152       // bytes per LDS buffer: A 16384 + B 32768

typedef __attribute__((ext_vector_type(8))) short frag8;
typedef __attribute__((ext_vector_type(4))) float floatx4;
typedef __attribute__((ext_vector_type(2))) float float2v;

__device__ __forceinline__ unsigned short f2bf(float f) {
    union { float f; uint32_t u; } v; v.f = f;
    uint32_t r = (v.u + 0x7FFFu + ((v.u >> 16) & 1u)) >> 16;
    return (unsigned short)r;
}
__device__ __forceinline__ float bf2f(unsigned short u) {
    union { uint32_t u; float f; } v; v.u = (uint32_t)u << 16;
    return v.f;
}
// decode a dword holding 2 bf16 -> {lo, hi} floats (2 VALU ops, exact)
__device__ __forceinline__ float2v bfpair(uint32_t d) {
    union { uint32_t u; float f; } lo, hi;
    lo.u = d << 16; hi.u = d & 0xFFFF0000u;
    return (float2v){lo.f, hi.f};
}

// packed fp32 math (full-rate, 2 FLOP-lanes per issue slot)
__device__ __forceinline__ float2v pk_mul(float2v a, float2v b) {
    float2v d;
    asm("v_pk_mul_f32 %0, %1, %2" : "=v"(d) : "v"(a), "v"(b));
    return d;
}
// acc += c * broadcast(x.lo)
__device__ __forceinline__ void pk_fma_lo(float2v& acc, float2v c, float2v x) {
    asm("v_pk_fma_f32 %0, %1, %2, %0 op_sel:[0,0,0] op_sel_hi:[1,0,1]"
        : "+v"(acc) : "v"(c), "v"(x));
}
// acc += c * broadcast(x.hi)
__device__ __forceinline__ void pk_fma_hi(float2v& acc, float2v c, float2v x) {
    asm("v_pk_fma_f32 %0, %1, %2, %0 op_sel:[0,1,0] op_sel_hi:[1,1,1]"
        : "+v"(acc) : "v"(c), "v"(x));
}

__device__ __forceinline__ void gl2lds16(const unsigned short* g, char* l) {
    __builtin_amdgcn_global_load_lds((const __attribute__((address_space(1))) void*)g,
                                     (__attribute__((address_space(3))) void*)l, 16, 0, 0);
}

// ---------- fp32 -> bf16 bulk convert ----------
__global__ __launch_bounds__(256) void k_cvt(const float* __restrict__ src,
                                             unsigned short* __restrict__ dst, int n4) {
    int i = blockIdx.x * 256 + threadIdx.x;
    if (i >= n4) return;
    float4 v = ((const float4*)src)[i];
    ushort4 o = make_ushort4(f2bf(v.x), f2bf(v.y), f2bf(v.z), f2bf(v.w));
    ((ushort4*)dst)[i] = o;
}

// ---------- CSR-by-destination ----------
// 8 edges/thread (grid-strided, coalesced): 8 independent atomic chains.
__global__ __launch_bounds__(256) void k_deg(const int* __restrict__ ei,
                                             int* __restrict__ deg, int E) {
    int t = blockIdx.x * 256 + threadIdx.x;
    int stride = gridDim.x * 256;
    int d[8];
#pragma unroll
    for (int j = 0; j < 8; ++j) {
        int e = t + j * stride;
        d[j] = (e < E) ? ei[E + e] : -1;
    }
#pragma unroll
    for (int j = 0; j < 8; ++j)
        if (d[j] >= 0) atomicAdd(&deg[d[j]], 1);
}

__global__ __launch_bounds__(256) void k_scan1(const int* __restrict__ deg,
                                               int* __restrict__ csum, int N) {
    __shared__ int sh[256];
    int n = blockIdx.x * 256 + threadIdx.x;
    sh[threadIdx.x] = (n < N) ? deg[n] : 0;
    __syncthreads();
    for (int off = 128; off > 0; off >>= 1) {
        if (threadIdx.x < off) sh[threadIdx.x] += sh[threadIdx.x + off];
        __syncthreads();
    }
    if (threadIdx.x == 0) csum[blockIdx.x] = sh[0];
}

// scan3 with the chunk-prefix scan folded in (scan2 kernel deleted):
// each block redundantly scans the <=256-entry csum array to get its own
// chunk base, then does the per-node scan. csum is read-only here.
__global__ __launch_bounds__(256) void k_scan3(const int* __restrict__ deg,
                                               const int* __restrict__ csum, int nch,
                                               int* __restrict__ rowptr,
                                               int* __restrict__ cursor,
                                               float* __restrict__ cnt, int N) {
    __shared__ int sh[256];
    int tid = threadIdx.x;
    int bid = blockIdx.x;
    int base;
    if (nch <= 256) {
        int c = (tid < nch) ? csum[tid] : 0;
        sh[tid] = c;
        __syncthreads();
        for (int off = 1; off < 256; off <<= 1) {
            int t = (tid >= off) ? sh[tid - off] : 0;
            __syncthreads();
            sh[tid] += t;
            __syncthreads();
        }
        base = sh[bid] - csum[bid];                 // exclusive prefix for this chunk
        if (bid == 0 && tid == 255) rowptr[N] = sh[255];   // grand total
        __syncthreads();                            // sh[] reused below
    } else {                                        // robustness fallback (unused at N=50000)
        int s = 0;
        for (int i = 0; i < bid; ++i) s += csum[i];
        base = s;
        if (bid == 0 && tid == 0) {
            int tot = 0;
            for (int i = 0; i < nch; ++i) tot += csum[i];
            rowptr[N] = tot;
        }
    }
    int n = bid * 256 + tid;
    int v = (n < N) ? deg[n] : 0;
    sh[tid] = v;
    __syncthreads();
    for (int off = 1; off < 256; off <<= 1) {
        int t = (tid >= off) ? sh[tid - off] : 0;
        __syncthreads();
        sh[tid] += t;
        __syncthreads();
    }
    int excl = sh[tid] - v + base;
    if (n < N) {
        rowptr[n] = excl;
        cursor[n] = excl;
        cnt[n] = (float)(v + 1);
    }
}

__global__ __launch_bounds__(256) void k_scatter(const int* __restrict__ ei,
                                                 const int* __restrict__ et,
                                                 const float* __restrict__ ea,
                                                 int* __restrict__ cursor,
                                                 int2* __restrict__ ep, int E) {
    int t = blockIdx.x * 256 + threadIdx.x;
    int stride = gridDim.x * 256;
    int src[8], dst[8], typ[8]; float w[8]; bool v[8];
#pragma unroll
    for (int j = 0; j < 8; ++j) {
        int e = t + j * stride;
        v[j] = (e < E);
        if (v[j]) { src[j] = ei[e]; dst[j] = ei[E + e]; typ[j] = et[e]; w[j] = ea[e]; }
    }
    int p[8];
#pragma unroll
    for (int j = 0; j < 8; ++j)
        if (v[j]) p[j] = atomicAdd(&cursor[dst[j]], 1);
#pragma unroll
    for (int j = 0; j < 8; ++j)
        if (v[j]) ep[p[j]] = make_int2(src[j] | (typ[j] << 24), __float_as_int(w[j]));
}

// ---------- weight prep: Wt[o][k] bf16, k = b*256+i (b=8 -> root) ----------
__global__ __launch_bounds__(256) void k_prep_w(const float* __restrict__ basis,
                                                const float* __restrict__ root,
                                                unsigned short* __restrict__ Wt) {
    __shared__ float tile[64][65];
    int k0 = blockIdx.x * 64, o0 = blockIdx.y * 64;
    const float* src = (k0 < BB * D) ? (basis + (size_t)k0 * D)
                                     : (root + (size_t)(k0 - BB * D) * D);
    int tid = threadIdx.x;
#pragma unroll
    for (int t = 0; t < 16; ++t) {
        int idx = t * 256 + tid;
        int kk = idx >> 6, oo = idx & 63;
        tile[kk][oo] = src[(size_t)kk * D + o0 + oo];
    }
    __syncthreads();
#pragma unroll
    for (int t = 0; t < 16; ++t) {
        int idx = t * 256 + tid;
        int oo = idx >> 6, kk = idx & 63;
        Wt[(size_t)(o0 + oo) * K9 + k0 + kk] = f2bf(tile[kk][oo]);
    }
}

// ---------- gather: one wave per node (one-shot dispatch; persistent form
// regressed in R9; NT stores regressed in R11 -- plain stores) ----------
__device__ __forceinline__ void edge_fma(float2v g2[4][4], float2v c0, float2v c1,
                                         float2v c2, float2v c3,
                                         float2v x0, float2v x1) {
    pk_fma_lo(g2[0][0], c0, x0); pk_fma_lo(g2[1][0], c1, x0);
    pk_fma_lo(g2[2][0], c2, x0); pk_fma_lo(g2[3][0], c3, x0);
    pk_fma_hi(g2[0][1], c0, x0); pk_fma_hi(g2[1][1], c1, x0);
    pk_fma_hi(g2[2][1], c2, x0); pk_fma_hi(g2[3][1], c3, x0);
    pk_fma_lo(g2[0][2], c0, x1); pk_fma_lo(g2[1][2], c1, x1);
    pk_fma_lo(g2[2][2], c2, x1); pk_fma_lo(g2[3][2], c3, x1);
    pk_fma_hi(g2[0][3], c0, x1); pk_fma_hi(g2[1][3], c1, x1);
    pk_fma_hi(g2[2][3], c2, x1); pk_fma_hi(g2[3][3], c3, x1);
}

__device__ __forceinline__ void do_edge(float2v g2[4][4], const float* att_s,
                                        int2 pe, uint2 ud) {
    int r = (unsigned)pe.x >> 24;
    const float4* Ar = (const float4*)&att_s[r * BB];
    float4 a0 = Ar[0], a1 = Ar[1];
    float we = __int_as_float(pe.y);
    float2v w2 = {we, we};
    float2v c0 = pk_mul(w2, (float2v){a0.x, a0.y});
    float2v c1 = pk_mul(w2, (float2v){a0.z, a0.w});
    float2v c2 = pk_mul(w2, (float2v){a1.x, a1.y});
    float2v c3 = pk_mul(w2, (float2v){a1.z, a1.w});
    float2v x0 = bfpair(ud.x), x1 = bfpair(ud.y);
    edge_fma(g2, c0, c1, c2, c3, x0, x1);
}

__global__ __launch_bounds__(256) void k_gather(
    const unsigned short* __restrict__ xb, const float* __restrict__ att,
    const int* __restrict__ rowptr, const int2* __restrict__ ep,
    unsigned short* __restrict__ G, int n0, int rows, int N) {
    __shared__ __align__(32) float att_s[RREL * BB];
    int tid = threadIdx.x;
    if (tid < RREL * BB) att_s[tid] = att[tid];
    __syncthreads();
    int wv = tid >> 6, lane = tid & 63;
    int rloc = blockIdx.x * 4 + wv;
    if (rloc >= rows) return;
    int n = n0 + rloc;
    unsigned short* gout = G + (size_t)rloc * KG + lane * 4;
    if (n >= N) {
        ushort4 z = make_ushort4(0, 0, 0, 0);
#pragma unroll
        for (int b = 0; b < BB; ++b) *(ushort4*)(gout + b * D) = z;
        return;
    }
    uint2 xu = *(const uint2*)&xb[(size_t)n * D + lane * 4];
    float2v xs0 = bfpair(xu.x), xs1 = bfpair(xu.y);
    float xv[4] = {xs0.x, xs0.y, xs1.x, xs1.y};

    float2v g2[4][4];
#pragma unroll
    for (int bp = 0; bp < 4; ++bp) {
        float2v ap = {att_s[(RREL - 1) * BB + 2 * bp],
                      att_s[(RREL - 1) * BB + 2 * bp + 1]};
#pragma unroll
        for (int j = 0; j < 4; ++j) {
            float2v xs = {xv[j], xv[j]};
            g2[bp][j] = ap * xs;
        }
    }

    int e0 = rowptr[n], e1 = rowptr[n + 1];
    int e = e0;
    for (; e + 4 <= e1; e += 4) {
        int2 pa = ep[e], pb = ep[e + 1], pc = ep[e + 2], pd = ep[e + 3];
        uint2 uA = *(const uint2*)&xb[(size_t)(pa.x & 0xFFFFFF) * D + lane * 4];
        uint2 uB = *(const uint2*)&xb[(size_t)(pb.x & 0xFFFFFF) * D + lane * 4];
        uint2 uC = *(const uint2*)&xb[(size_t)(pc.x & 0xFFFFFF) * D + lane * 4];
        uint2 uD = *(const uint2*)&xb[(size_t)(pd.x & 0xFFFFFF) * D + lane * 4];
        __builtin_amdgcn_sched_barrier(0);   // loads above, FMAs below
        do_edge(g2, att_s, pa, uA);
        do_edge(g2, att_s, pb, uB);
        do_edge(g2, att_s, pc, uC);
        do_edge(g2, att_s, pd, uD);
    }
    if (e + 2 <= e1) {
        int2 pa = ep[e], pb = ep[e + 1];
        uint2 uA = *(const uint2*)&xb[(size_t)(pa.x & 0xFFFFFF) * D + lane * 4];
        uint2 uB = *(const uint2*)&xb[(size_t)(pb.x & 0xFFFFFF) * D + lane * 4];
        __builtin_amdgcn_sched_barrier(0);
        do_edge(g2, att_s, pa, uA);
        do_edge(g2, att_s, pb, uB);
        e += 2;
    }
    if (e < e1) {
        int2 pa = ep[e];
        uint2 uA = *(const uint2*)&xb[(size_t)(pa.x & 0xFFFFFF) * D + lane * 4];
        do_edge(g2, att_s, pa, uA);
    }
#pragma unroll
    for (int bp = 0; bp < 4; ++bp) {
        ushort4 o0 = make_ushort4(f2bf(g2[bp][0].x), f2bf(g2[bp][1].x),
                                  f2bf(g2[bp][2].x), f2bf(g2[bp][3].x));
        *(ushort4*)(gout + (2 * bp) * D) = o0;
        ushort4 o1 = make_ushort4(f2bf(g2[bp][0].y), f2bf(g2[bp][1].y),
                                  f2bf(g2[bp][2].y), f2bf(g2[bp][3].y));
        *(ushort4*)(gout + (2 * bp + 1) * D) = o1;
    }
}

// ---------- fused GEMM (128x256, K=2304, bf16 MFMA) + mean + residual + LN + ReLU ----------
// R5-proven K-loop structure (FROZEN: R6 fat-waves and R7 counted-vmcnt both
// regressed). New in R12: K-steps 0..31 read G (edge-gathered, 8 blocks);
// K-steps 32..35 (root term) stage A directly from xb (L3-hot) into a SEPARATE
// static accumulator acc2 -- removes G's 9th block (11% of gather+gemm G
// traffic) and the cnt*x/cnt round-trip. val = acc*inv + acc2 + resid + bias.
__global__ __launch_bounds__(1024, 4) void k_gemm(
    const unsigned short* __restrict__ G, const unsigned short* __restrict__ xb,
    const unsigned short* __restrict__ Wt,
    const float* __restrict__ hin, const float* __restrict__ cnt,
    const float* __restrict__ bias, const float* __restrict__ gln,
    const float* __restrict__ bln, float* __restrict__ hout,
    unsigned short* __restrict__ houtb, int n0, int N) {
    __shared__ __align__(16) char smem[2 * BUFB];
    // post-loop aliases (staging region idle during the epilogue)
    float* ps   = (float*)smem;          // [128][4] row-sum partials per col-wave
    float* pq   = ps + 512;              // [128][4]
    float* mu_s = ps + 1024;             // [128]
    float* rs_s = ps + 1152;             // [128]

    int tid = threadIdx.x;
    int wv = tid >> 6, lane = tid & 63;
    int quad = lane >> 4, l16 = lane & 15;
    int wm = wv >> 2, wn = wv & 3;       // wave -> 32x64 sub-tile of 128x256
    int grow = blockIdx.x * 128;         // chunk-local row base
    int nb = n0 + grow;                  // global node base

    // staging addresses (XOR-swizzled 16B granules: slot = g ^ (row&7))
    int arow_s = tid >> 3, aslot_s = tid & 7;     // A: 128 rows x 8 granules
    int swzA = (aslot_s ^ (arow_s & 7)) << 3;
    const unsigned short* gAG = G + (size_t)(grow + arow_s) * KG + swzA;
    const unsigned short* gAX = xb + (size_t)(nb + arow_s) * D + swzA;
    char* lA = smem + (tid << 4);
    const unsigned short* gB[2]; char* lB[2];
#pragma unroll
    for (int t = 0; t < 2; ++t) {                  // B: 256 rows x 8 granules
        int c = t * 1024 + tid;
        int brow = c >> 3, bslot = c & 7;
        gB[t] = Wt + (size_t)brow * K9 + ((bslot ^ (brow & 7)) << 3);
        lB[t] = smem + 16384 + (c << 4);
    }

    floatx4 acc[2][4];    // K-steps 0..31 (edge aggregate, scaled by 1/cnt)
    floatx4 acc2[2][4];   // K-steps 32..35 (x @ root, unscaled)
#pragma unroll
    for (int mf = 0; mf < 2; ++mf)
#pragma unroll
        for (int nf = 0; nf < 4; ++nf) {
            acc[mf][nf]  = (floatx4){0.f, 0.f, 0.f, 0.f};
            acc2[mf][nf] = (floatx4){0.f, 0.f, 0.f, 0.f};
        }

    auto STAGE = [&](int it, int soff) {
        const unsigned short* sa =
            (it < 32) ? (gAG + it * 64) : (gAX + (it - 32) * 64);
        gl2lds16(sa, lA + soff);
        int koff = it * 64;
        gl2lds16(gB[0] + koff, lB[0] + soff);
        gl2lds16(gB[1] + koff, lB[1] + soff);
    };
    auto COMPUTE = [&](int soff, floatx4 (&ac)[2][4]) {
        const char* Ab = smem + soff;
        const char* Bb = Ab + 16384;
#pragma unroll
        for (int kc = 0; kc < 2; ++kc) {
            int g = kc * 4 + quad;
            frag8 a[2], b[4];
#pragma unroll
            for (int mf = 0; mf < 2; ++mf) {
                int arow = wm * 32 + mf * 16 + l16;
                a[mf] = *(const frag8*)(Ab + arow * 128 + ((g ^ (arow & 7)) << 4));
            }
#pragma unroll
            for (int nf = 0; nf < 4; ++nf) {
                int brow = wn * 64 + nf * 16 + l16;
                b[nf] = *(const frag8*)(Bb + brow * 128 + ((g ^ (brow & 7)) << 4));
            }
#pragma unroll
            for (int mf = 0; mf < 2; ++mf)
#pragma unroll
                for (int nf = 0; nf < 4; ++nf)
                    ac[mf][nf] = __builtin_amdgcn_mfma_f32_16x16x32_bf16(
                        a[mf], b[nf], ac[mf][nf], 0, 0, 0);
        }
    };

    STAGE(0, 0);
    __syncthreads();
    // steps 0..31 -> acc (A from G)
    for (int it = 0; it < 32; it += 2) {
        STAGE(it + 1, BUFB);                 // odd step -> buf1
        COMPUTE(0, acc);
        __syncthreads();
        STAGE(it + 2, 0);                    // even step -> buf0 (it+2==32 -> xb src)
        COMPUTE(BUFB, acc);
        __syncthreads();
    }
    // steps 32..35 -> acc2 (A from xb); step 32 already staged in buf0
    for (int it = 32; it < NT; it += 2) {
        STAGE(it + 1, BUFB);
        COMPUTE(0, acc2);
        __syncthreads();
        if (it + 2 < NT) STAGE(it + 2, 0);
        COMPUTE(BUFB, acc2);
        __syncthreads();
    }

    // ---- pass 1: val = acc/cnt + acc2 + residual + bias; wave-local LN partials ----
    int col[4]; float bic[4];
#pragma unroll
    for (int nf = 0; nf < 4; ++nf) {
        col[nf] = wn * 64 + nf * 16 + l16;
        bic[nf] = bias[col[nf]];
    }
#pragma unroll
    for (int mf = 0; mf < 2; ++mf) {
#pragma unroll
        for (int r = 0; r < 4; ++r) {
            int row = wm * 32 + mf * 16 + quad * 4 + r;
            int n = nb + row;
            float s = 0.f, sq = 0.f;
            if (n < N) {
                float inv = 1.0f / cnt[n];
                const float* hp = hin + (size_t)n * D;
#pragma unroll
                for (int nf = 0; nf < 4; ++nf) {
                    float v = acc[mf][nf][r] * inv + acc2[mf][nf][r]
                            + hp[col[nf]] + bic[nf];
                    acc[mf][nf][r] = v;
                    s += v; sq += v * v;
                }
            }
            s += __shfl_xor(s, 1); sq += __shfl_xor(sq, 1);
            s += __shfl_xor(s, 2); sq += __shfl_xor(sq, 2);
            s += __shfl_xor(s, 4); sq += __shfl_xor(sq, 4);
            s += __shfl_xor(s, 8); sq += __shfl_xor(sq, 8);
            if (l16 == 0) {
                ps[row * 4 + wn] = s;
                pq[row * 4 + wn] = sq;
            }
        }
    }
    __syncthreads();
    if (tid < 128) {
        float s  = ps[tid * 4] + ps[tid * 4 + 1] + ps[tid * 4 + 2] + ps[tid * 4 + 3];
        float sq = pq[tid * 4] + pq[tid * 4 + 1] + pq[tid * 4 + 2] + pq[tid * 4 + 3];
        float mu = s * (1.f / D);
        mu_s[tid] = mu;
        rs_s[tid] = rsqrtf(sq * (1.f / D) - mu * mu + LN_EPS);
    }
    __syncthreads();

    // ---- pass 2: normalize + ReLU + store (fp32, optional bf16 copy) ----
    float gc[4], bc[4];
#pragma unroll
    for (int nf = 0; nf < 4; ++nf) {
        gc[nf] = gln[col[nf]];
        bc[nf] = bln[col[nf]];
    }
#pragma unroll
    for (int mf = 0; mf < 2; ++mf) {
#pragma unroll
        for (int r = 0; r < 4; ++r) {
            int row = wm * 32 + mf * 16 + quad * 4 + r;
            int n = nb + row;
            if (n >= N) continue;
            float mu = mu_s[row], rs = rs_s[row];
            float* op = hout + (size_t)n * D;
#pragma unroll
            for (int nf = 0; nf < 4; ++nf) {
                float o = fmaxf((acc[mf][nf][r] - mu) * rs * gc[nf] + bc[nf], 0.f);
                op[col[nf]] = o;
                if (houtb) houtb[(size_t)n * D + col[nf]] = f2bf(o);
            }
        }
    }
}

extern "C" void kernel_launch(void* const* d_in, const int* in_sizes, int n_in,
                              void* d_out, int out_size, void* d_ws, size_t ws_size,
                              hipStream_t stream) {
    const float* x      = (const float*)d_in[0];
    const int*   ei     = (const int*)d_in[1];
    const int*   et     = (const int*)d_in[2];
    const float* ea     = (const float*)d_in[3];
    const float* basis1 = (const float*)d_in[4];
    const float* att1   = (const float*)d_in[5];
    const float* root1  = (const float*)d_in[6];
    const float* bias1  = (const float*)d_in[7];
    const float* g1     = (const float*)d_in[8];
    const float* b1     = (const float*)d_in[9];
    const float* basis2 = (const float*)d_in[10];
    const float* att2   = (const float*)d_in[11];
    const float* root2  = (const float*)d_in[12];
    const float* bias2  = (const float*)d_in[13];
    const float* g2     = (const float*)d_in[14];
    const float* b2     = (const float*)d_in[15];
    float* out = (float*)d_out;

    int N = in_sizes[0] / D;
    int E = in_sizes[2];
    int nch = (N + 255) / 256;
    int Mp = ((N + 63) / 64) * 64;
    int T = Mp / 64;
    int Tpad = (T + 1) & ~1;             // even # of 64-row tiles (gather zero-fills pads)

    char* p = (char*)d_ws;
    size_t used = 0;
    auto alloc = [&](size_t bytes) {
        char* q = p;
        size_t a = (bytes + 255) & ~(size_t)255;
        p += a; used += a;
        return q;
    };
    float*          h1     = (float*)alloc((size_t)N * D * 4);
    unsigned short* xb     = (unsigned short*)alloc((size_t)N * D * 2);
    unsigned short* h1b    = (unsigned short*)alloc((size_t)N * D * 2);
    unsigned short* Wt     = (unsigned short*)alloc((size_t)K9 * D * 2);
    int*            deg    = (int*)alloc((size_t)N * 4);
    int*            rowptr = (int*)alloc((size_t)(N + 1) * 4);
    int*            cursor = (int*)alloc((size_t)N * 4);
    float*          cnt    = (float*)alloc((size_t)N * 4);
    int2*           ep     = (int2*)alloc((size_t)E * 8);
    int*            csum   = (int*)alloc((size_t)nch * 4);
    size_t remain = (ws_size > used + 256) ? (ws_size - used - 256) : 0;
    size_t tile_bytes = (size_t)64 * KG * 2;     // G rows are KG=2048 wide now
    int ct_max = (int)(remain / tile_bytes);
    if (ct_max < 2) ct_max = 2;
    if (ct_max > Tpad) ct_max = Tpad;
    unsigned short* G = (unsigned short*)alloc((size_t)ct_max * tile_bytes);

    // balanced, even chunk size (in 64-row tiles) -> each gemm grid <= ~256
    // blocks of 128 rows, one round per chunk, rows % 128 == 0 per chunk.
    int nch2 = (Tpad + ct_max - 1) / ct_max;
    int ct = (Tpad + nch2 - 1) / nch2;
    ct = (ct + 1) & ~1;
    if (ct > ct_max) ct = ct_max & ~1;
    if (ct < 2) ct = 2;

    hipMemsetAsync(deg, 0, (size_t)N * 4, stream);
    int gE8 = (E + 2047) / 2048;         // 8 edges/thread
    k_deg<<<gE8, 256, 0, stream>>>(ei, deg, E);
    k_scan1<<<nch, 256, 0, stream>>>(deg, csum, N);
    k_scan3<<<nch, 256, 0, stream>>>(deg, csum, nch, rowptr, cursor, cnt, N);
    k_scatter<<<gE8, 256, 0, stream>>>(ei, et, ea, cursor, ep, E);
    k_cvt<<<(N * D / 4 + 255) / 256, 256, 0, stream>>>(x, xb, N * D / 4);

    const float* bas[2]  = {basis1, basis2};
    const float* attp[2] = {att1, att2};
    const float* rt[2]   = {root1, root2};
    const float* bi[2]   = {bias1, bias2};
    const float* lg[2]   = {g1, g2};
    const float* lb[2]   = {b1, b2};
    const unsigned short* gin[2] = {xb, h1b};
    const float* hres[2] = {x, h1};
    float*          hof[2] = {h1, out};
    unsigned short* hob[2] = {h1b, nullptr};

    for (int L = 0; L < 2; ++L) {
        k_prep_w<<<dim3(K9 / 64, D / 64), 256, 0, stream>>>(bas[L], rt[L], Wt);
        for (int c0 = 0; c0 < Tpad; c0 += ct) {
            int tiles = (Tpad - c0 < ct) ? (Tpad - c0) : ct;
            int rows = tiles * 64;       // multiple of 128 by construction
            int n0 = c0 * 64;
            k_gather<<<rows / 4, 256, 0, stream>>>(gin[L], attp[L], rowptr, ep,
                                                   G, n0, rows, N);
            k_gemm<<<rows / 128, 1024, 0, stream>>>(G, gin[L], Wt, hres[L], cnt,
                                                    bi[L], lg[L], lb[L], hof[L],
                                                    hob[L], n0, N);
        }
    }
}